// Round 1
// 481.858 us; speedup vs baseline: 1.2724x; 1.2724x over previous
//
#include <hip/hip_runtime.h>
#include <hip/hip_bf16.h>

typedef __bf16 bf16_t;
typedef __bf16 bf16x4 __attribute__((ext_vector_type(4)));
typedef __bf16 bf16x8 __attribute__((ext_vector_type(8)));
typedef float f32x4 __attribute__((ext_vector_type(4)));

#define SCALE 0.08838834764831845f
#define NEG_MASK -1e10f      // matches reference; exp underflows to exact 0
#define NEG_INIT -3e38f      // running-max init; finite so no inf-inf paths

constexpr int H_ = 16;
constexpr int KH_ = 4;
constexpr int D_ = 128;
constexpr int BM = 64;   // q rows per workgroup
constexpr int BN = 64;   // keys per tile

// LDS strides in bf16 elements; multiples of 4 (8B) keep stores aligned,
// pads break power-of-2 bank aliasing for the b128 fragment reads.
constexpr int K_STRIDE = 136;  // K tile [64][128]+pad
constexpr int V_STRIDE = 72;   // V^T tile [128][64]+pad
constexpr int P_STRIDE = 72;   // per-wave P tile [16][64]+pad

// Inputs fp32 (R5: bf16 view NaNs -> fp32 storage proven).
// Output fp32 (reference returns fp32).
//
// R6 (this round): swapped-operand MFMA structure.
//   QK^T computed as S^T = mfma(K, Q)  -> D[key][q], q = lane&15
//   PV   computed as O^T = mfma(V^T, P^T) -> D[d][q],  q = lane&15
// Each lane owns ONE q-row: softmax is 15 in-reg fmax + 2 shfl (was 32 shfl),
// m/l/alpha are per-lane scalars (no broadcast), P staged as bf16x4 vectors,
// and the P round-trip barrier is dropped (wave-private buffer).
__global__ __launch_bounds__(256)
void fa_fwd(const float* __restrict__ qg,
            const float* __restrict__ kg,
            const float* __restrict__ vg,
            float* __restrict__ og,
            int S)
{
    const int qt  = blockIdx.x;          // q tile within sequence
    const int h   = blockIdx.y;
    const int b   = blockIdx.z;
    const int kh  = h / (H_ / KH_);      // GQA: 4 q-heads share one kv-head

    const int tid  = threadIdx.x;
    const int wid  = tid >> 6;
    const int lane = tid & 63;
    const int quad = lane >> 4;
    const int l16  = lane & 15;

    __shared__ bf16_t lds_k[BN * K_STRIDE];
    __shared__ bf16_t lds_v[D_ * V_STRIDE];      // transposed: [d][key]
    __shared__ bf16_t lds_p[4 * 16 * P_STRIDE];  // per-wave P staging

    const int  q0   = qt * BM;
    const long tok0 = (long)b * S;
    const int  qrow = q0 + wid * 16 + l16;       // the q-row this lane owns

    // ---- Q fragments (B-layout for swapped QK^T; same load as before:
    // lane l16 holds row qrow, d-slice kc*32 + quad*8 .. +8).
    bf16x8 qfrag[4];
    {
        const float* qp = qg + ((tok0 + qrow) * H_ + h) * D_;
        #pragma unroll
        for (int kc = 0; kc < 4; ++kc) {
            f32x4 a = *reinterpret_cast<const f32x4*>(qp + kc * 32 + quad * 8);
            f32x4 c = *reinterpret_cast<const f32x4*>(qp + kc * 32 + quad * 8 + 4);
            #pragma unroll
            for (int j = 0; j < 4; ++j) {
                qfrag[kc][j]     = (bf16_t)a[j];
                qfrag[kc][j + 4] = (bf16_t)c[j];
            }
        }
    }

    // O^T accumulator: oacc[dt][r] = O[q = l16][d = dt*16 + quad*4 + r]
    f32x4 oacc[8];
    #pragma unroll
    for (int i = 0; i < 8; ++i) oacc[i] = (f32x4){0.f, 0.f, 0.f, 0.f};
    float m_i = NEG_INIT, l_i = 0.f;     // per-lane scalars (one q-row/lane)

    const int nkt = qt + 1;               // causal: only tiles up to diagonal
    for (int kt = 0; kt < nkt; ++kt) {
        const int kst = kt * BN;
        __syncthreads();                  // prior iter's LDS reads done

        // ---- stage K tile [64][128]: fp32 float4 loads -> bf16x4 LDS stores
        #pragma unroll
        for (int it = 0; it < 8; ++it) {
            int c = it * 256 + tid;       // 0..2047
            int n = c >> 5, ch = c & 31;  // row 0..63, float4-chunk 0..31
            long row = tok0 + kst + n;
            f32x4 t = *reinterpret_cast<const f32x4*>(
                kg + (row * KH_ + kh) * D_ + ch * 4);
            bf16x4 w;
            w[0] = (bf16_t)t[0]; w[1] = (bf16_t)t[1];
            w[2] = (bf16_t)t[2]; w[3] = (bf16_t)t[3];
            *reinterpret_cast<bf16x4*>(&lds_k[n * K_STRIDE + ch * 4]) = w;
        }
        // ---- stage V transposed: lds_v[d][key]; float4 load, bf16 scatter
        {
            int n = tid & 63;
            long row = tok0 + kst + n;
            const float* vp = vg + (row * KH_ + kh) * D_;
            #pragma unroll
            for (int it = 0; it < 8; ++it) {
                int dch = (tid >> 6) * 8 + it;   // 0..31, d = dch*4..+3
                f32x4 t = *reinterpret_cast<const f32x4*>(vp + dch * 4);
                #pragma unroll
                for (int j = 0; j < 4; ++j)
                    lds_v[(dch * 4 + j) * V_STRIDE + n] = (bf16_t)t[j];
            }
        }
        __syncthreads();

        // ---- S^T = K Q^T  (per wave: 64 keys x 16 q-rows)
        // A = K tile (lane l16 = key row), B = Q^T (lane l16 = q col).
        f32x4 s[4];
        #pragma unroll
        for (int nt = 0; nt < 4; ++nt) {
            f32x4 acc = (f32x4){0.f, 0.f, 0.f, 0.f};
            #pragma unroll
            for (int kc = 0; kc < 4; ++kc) {
                bf16x8 kf = *reinterpret_cast<const bf16x8*>(
                    &lds_k[(nt * 16 + l16) * K_STRIDE + kc * 32 + quad * 8]);
                acc = __builtin_amdgcn_mfma_f32_16x16x32_bf16(kf, qfrag[kc], acc, 0, 0, 0);
            }
            s[nt] = acc;   // s[nt][r] = S[qrow][key = kst + nt*16 + quad*4 + r]
        }

        // ---- online softmax, fully per-lane (lane owns q-row qrow)
        const bool diag = (kst + BN > q0);   // only diagonal tile needs mask
        if (diag) {
            #pragma unroll
            for (int nt = 0; nt < 4; ++nt)
                #pragma unroll
                for (int r = 0; r < 4; ++r) {
                    const int key = kst + nt * 16 + quad * 4 + r;
                    float x = s[nt][r] * SCALE;
                    s[nt][r] = (key > qrow) ? NEG_MASK : x;
                }
        } else {
            #pragma unroll
            for (int nt = 0; nt < 4; ++nt)
                #pragma unroll
                for (int r = 0; r < 4; ++r)
                    s[nt][r] *= SCALE;
        }
        // max over 16 in-register values, then combine the 4 quads
        float mx01 = fmaxf(fmaxf(s[0][0], s[0][1]), fmaxf(s[0][2], s[0][3]));
        float mx11 = fmaxf(fmaxf(s[1][0], s[1][1]), fmaxf(s[1][2], s[1][3]));
        float mx21 = fmaxf(fmaxf(s[2][0], s[2][1]), fmaxf(s[2][2], s[2][3]));
        float mx31 = fmaxf(fmaxf(s[3][0], s[3][1]), fmaxf(s[3][2], s[3][3]));
        float mx = fmaxf(fmaxf(mx01, mx11), fmaxf(mx21, mx31));
        mx = fmaxf(mx, __shfl_xor(mx, 16));
        mx = fmaxf(mx, __shfl_xor(mx, 32));

        const float mn    = fmaxf(m_i, mx);
        const float alpha = __expf(m_i - mn);
        float rs = 0.f;
        #pragma unroll
        for (int nt = 0; nt < 4; ++nt)
            #pragma unroll
            for (int r = 0; r < 4; ++r) {
                float p = __expf(s[nt][r] - mn);
                s[nt][r] = p;
                rs += p;
            }
        rs += __shfl_xor(rs, 16);
        rs += __shfl_xor(rs, 32);
        l_i = l_i * alpha + rs;
        m_i = mn;
        #pragma unroll
        for (int dt = 0; dt < 8; ++dt)
            #pragma unroll
            for (int r = 0; r < 4; ++r)
                oacc[dt][r] *= alpha;     // alpha is per-lane: no broadcast

        // ---- P -> LDS, wave-private (keys quad*4+r are reg-contiguous ->
        // bf16x4 vector stores). No block barrier: same-wave lgkmcnt ordering
        // (compiler-inserted) covers the cross-lane LDS dependency.
        bf16_t* pw = &lds_p[wid * 16 * P_STRIDE];
        #pragma unroll
        for (int nt = 0; nt < 4; ++nt) {
            bf16x4 w;
            #pragma unroll
            for (int r = 0; r < 4; ++r) w[r] = (bf16_t)s[nt][r];
            *reinterpret_cast<bf16x4*>(&pw[l16 * P_STRIDE + nt * 16 + quad * 4]) = w;
        }

        // ---- O^T += V^T P^T   (A = V^T: lane l16 = d row; B = P^T: lane
        // l16 = q col. Both read expressions identical to the old kernel;
        // only the operand order flips.)
        #pragma unroll
        for (int kc = 0; kc < 2; ++kc) {
            bf16x8 pf = *reinterpret_cast<const bf16x8*>(
                &pw[l16 * P_STRIDE + kc * 32 + quad * 8]);
            #pragma unroll
            for (int dt = 0; dt < 8; ++dt) {
                bf16x8 vf = *reinterpret_cast<const bf16x8*>(
                    &lds_v[(dt * 16 + l16) * V_STRIDE + kc * 32 + quad * 8]);
                oacc[dt] = __builtin_amdgcn_mfma_f32_16x16x32_bf16(vf, pf, oacc[dt], 0, 0, 0);
            }
        }
    }

    // ---- epilogue: O /= l, store FP32 as f32x4 (d = dt*16 + quad*4 + r)
    const float inv = 1.0f / l_i;
    float* op = og + ((tok0 + qrow) * H_ + h) * D_;
    #pragma unroll
    for (int dt = 0; dt < 8; ++dt) {
        f32x4 o;
        #pragma unroll
        for (int r = 0; r < 4; ++r) o[r] = oacc[dt][r] * inv;
        *reinterpret_cast<f32x4*>(&op[dt * 16 + quad * 4]) = o;
    }
}

extern "C" void kernel_launch(void* const* d_in, const int* in_sizes, int n_in,
                              void* d_out, int out_size, void* d_ws, size_t ws_size,
                              hipStream_t stream) {
    const float* q = (const float*)d_in[0];   // fp32 (proven R5)
    const float* k = (const float*)d_in[1];
    const float* v = (const float*)d_in[2];
    float* out = (float*)d_out;               // fp32, per reference dtype

    const int B = in_sizes[3] - 1;
    const int T = in_sizes[0] / (H_ * D_);
    const int S = T / B;

    dim3 grid(S / BM, H_, B);
    fa_fwd<<<grid, 256, 0, stream>>>(q, k, v, out, S);
}

// Round 3
// 467.364 us; speedup vs baseline: 1.3119x; 1.0310x over previous
//
#include <hip/hip_runtime.h>
#include <hip/hip_bf16.h>

typedef __bf16 bf16_t;
typedef __bf16 bf16x4 __attribute__((ext_vector_type(4)));
typedef __bf16 bf16x8 __attribute__((ext_vector_type(8)));
typedef float f32x4 __attribute__((ext_vector_type(4)));

#define SCALE 0.08838834764831845f
#define NEG_MASK -1e10f      // matches reference; exp underflows to exact 0
#define NEG_INIT -3e38f      // running-max init; finite so no inf-inf paths
#define DEFER_THR 8.0f       // T13: tolerate m staleness up to e^8 in P

constexpr int H_ = 16;
constexpr int KH_ = 4;
constexpr int D_ = 128;
constexpr int BM = 64;   // q rows per workgroup
constexpr int BN = 64;   // keys per tile

// LDS strides in bf16 elements; multiples of 8 keep b128 reads 16B-aligned,
// pads break power-of-2 bank aliasing for the fragment reads.
constexpr int K_STRIDE = 136;  // K tile [64][128]+pad
constexpr int V_STRIDE = 72;   // V^T tile [128][64]+pad
constexpr int P_STRIDE = 72;   // per-wave P tile [16][64]+pad

// R6: swapped-operand MFMA (S^T = mfma(K,Q), O^T = mfma(V^T,P^T)); lane owns
//     one q-row -> softmax per-lane, 4 shfl/tile, no 3rd barrier. 545->402us.
// R7 (resubmitted; R2 bench was a broker timeout, kernel never measured):
//   * T14 async-stage: tile kt+1's global loads issued into registers BEFORE
//     computing tile kt; cvt+LDS-commit after the post-compute barrier. HBM
//     latency (~900cy) hides under compute (~2000cy).
//   * hoisted per-thread staging pointers: per-tile addr = base + uniform
//     offset (no per-load 64-bit mul chains).
//   * T5 setprio around MFMA clusters (prefetch creates wave role-split).
//   * T13 defer-max: skip O-rescale when __all(mx - m_i <= 8).
__global__ __launch_bounds__(256)
void fa_fwd(const float* __restrict__ qg,
            const float* __restrict__ kg,
            const float* __restrict__ vg,
            float* __restrict__ og,
            int S)
{
    const int qt  = blockIdx.x;          // q tile within sequence
    const int h   = blockIdx.y;
    const int b   = blockIdx.z;
    const int kh  = h / (H_ / KH_);      // GQA: 4 q-heads share one kv-head

    const int tid  = threadIdx.x;
    const int wid  = tid >> 6;
    const int lane = tid & 63;
    const int quad = lane >> 4;
    const int l16  = lane & 15;

    __shared__ bf16_t lds_k[BN * K_STRIDE];
    __shared__ bf16_t lds_v[D_ * V_STRIDE];      // transposed: [d][key]
    __shared__ bf16_t lds_p[4 * 16 * P_STRIDE];  // per-wave P staging

    const int  q0   = qt * BM;
    const long tok0 = (long)b * S;
    const int  qrow = q0 + wid * 16 + l16;       // the q-row this lane owns

    // ---- hoisted staging bases (per-thread; advance by uniform offsets)
    // K: row n = it*8 + (tid>>5), chunk ch = tid&31  (f32x4 at d=ch*4)
    const float* kbase = kg + (((long)(tok0 + (tid >> 5))) * KH_ + kh) * D_
                            + (tid & 31) * 4;
    // V: key n = tid&63, d-chunk dch = (tid>>6)*8 + it (f32x4 at d=dch*4)
    const float* vbase = vg + (((long)(tok0 + (tid & 63))) * KH_ + kh) * D_
                            + (tid >> 6) * 32;
    bf16_t* kw = &lds_k[(tid >> 5) * K_STRIDE + (tid & 31) * 4];
    bf16_t* vw = &lds_v[(tid >> 6) * 32 * V_STRIDE + (tid & 63)];

    f32x4 kbuf[8], vbuf[8];              // in-flight staging registers

    // ---- Q fragments (B-layout for swapped QK^T)
    bf16x8 qfrag[4];
    {
        const float* qp = qg + ((tok0 + qrow) * H_ + h) * D_;
        #pragma unroll
        for (int kc = 0; kc < 4; ++kc) {
            f32x4 a = *reinterpret_cast<const f32x4*>(qp + kc * 32 + quad * 8);
            f32x4 c = *reinterpret_cast<const f32x4*>(qp + kc * 32 + quad * 8 + 4);
            #pragma unroll
            for (int j = 0; j < 4; ++j) {
                qfrag[kc][j]     = (bf16_t)a[j];
                qfrag[kc][j + 4] = (bf16_t)c[j];
            }
        }
    }

    // O^T accumulator: oacc[dt][r] = O[q = l16][d = dt*16 + quad*4 + r]
    f32x4 oacc[8];
    #pragma unroll
    for (int i = 0; i < 8; ++i) oacc[i] = (f32x4){0.f, 0.f, 0.f, 0.f};
    float m_i = NEG_INIT, l_i = 0.f;     // per-lane scalars (one q-row/lane)

    const int nkt = qt + 1;               // causal: only tiles up to diagonal

    // ---- prologue: stage tile 0
    {
        #pragma unroll
        for (int it = 0; it < 8; ++it)
            kbuf[it] = *reinterpret_cast<const f32x4*>(kbase + it * 8 * KH_ * D_);
        #pragma unroll
        for (int it = 0; it < 8; ++it)
            vbuf[it] = *reinterpret_cast<const f32x4*>(vbase + it * 4);
        #pragma unroll
        for (int it = 0; it < 8; ++it) {
            bf16x4 w;
            #pragma unroll
            for (int j = 0; j < 4; ++j) w[j] = (bf16_t)kbuf[it][j];
            *reinterpret_cast<bf16x4*>(&kw[it * 8 * K_STRIDE]) = w;
        }
        #pragma unroll
        for (int it = 0; it < 8; ++it)
            #pragma unroll
            for (int j = 0; j < 4; ++j)
                vw[(it * 4 + j) * V_STRIDE] = (bf16_t)vbuf[it][j];
    }
    __syncthreads();

    for (int kt = 0; kt < nkt; ++kt) {
        const int kst = kt * BN;
        const bool more = (kt + 1 < nkt);

        // ---- T14: issue next tile's global loads NOW (regs); commit later
        if (more) {
            const long off = (long)(kst + BN) * KH_ * D_;
            const float* kp = kbase + off;
            const float* vp = vbase + off;
            #pragma unroll
            for (int it = 0; it < 8; ++it)
                kbuf[it] = *reinterpret_cast<const f32x4*>(kp + it * 8 * KH_ * D_);
            #pragma unroll
            for (int it = 0; it < 8; ++it)
                vbuf[it] = *reinterpret_cast<const f32x4*>(vp + it * 4);
        }

        // ---- S^T = K Q^T  (per wave: 64 keys x 16 q-rows)
        f32x4 s[4];
        __builtin_amdgcn_s_setprio(1);
        #pragma unroll
        for (int nt = 0; nt < 4; ++nt) {
            f32x4 acc = (f32x4){0.f, 0.f, 0.f, 0.f};
            #pragma unroll
            for (int kc = 0; kc < 4; ++kc) {
                bf16x8 kf = *reinterpret_cast<const bf16x8*>(
                    &lds_k[(nt * 16 + l16) * K_STRIDE + kc * 32 + quad * 8]);
                acc = __builtin_amdgcn_mfma_f32_16x16x32_bf16(kf, qfrag[kc], acc, 0, 0, 0);
            }
            s[nt] = acc;   // s[nt][r] = S[qrow][key = kst + nt*16 + quad*4 + r]
        }
        __builtin_amdgcn_s_setprio(0);

        // ---- online softmax, fully per-lane (lane owns q-row qrow)
        const bool diag = (kst + BN > q0);   // only diagonal tile needs mask
        if (diag) {
            #pragma unroll
            for (int nt = 0; nt < 4; ++nt)
                #pragma unroll
                for (int r = 0; r < 4; ++r) {
                    const int key = kst + nt * 16 + quad * 4 + r;
                    float x = s[nt][r] * SCALE;
                    s[nt][r] = (key > qrow) ? NEG_MASK : x;
                }
        } else {
            #pragma unroll
            for (int nt = 0; nt < 4; ++nt)
                #pragma unroll
                for (int r = 0; r < 4; ++r)
                    s[nt][r] *= SCALE;
        }
        float mx0 = fmaxf(fmaxf(s[0][0], s[0][1]), fmaxf(s[0][2], s[0][3]));
        float mx1 = fmaxf(fmaxf(s[1][0], s[1][1]), fmaxf(s[1][2], s[1][3]));
        float mx2 = fmaxf(fmaxf(s[2][0], s[2][1]), fmaxf(s[2][2], s[2][3]));
        float mx3 = fmaxf(fmaxf(s[3][0], s[3][1]), fmaxf(s[3][2], s[3][3]));
        float mx = fmaxf(fmaxf(mx0, mx1), fmaxf(mx2, mx3));
        mx = fmaxf(mx, __shfl_xor(mx, 16));
        mx = fmaxf(mx, __shfl_xor(mx, 32));

        // T13 defer-max: if no row grew its max by >THR, keep stale m_i
        // (P bounded by e^8; bf16 relative precision unchanged) and skip
        // the O-rescale pass entirely.
        if (__all(mx - m_i <= DEFER_THR)) {
            float rs = 0.f;
            #pragma unroll
            for (int nt = 0; nt < 4; ++nt)
                #pragma unroll
                for (int r = 0; r < 4; ++r) {
                    float p = __expf(s[nt][r] - m_i);
                    s[nt][r] = p;
                    rs += p;
                }
            rs += __shfl_xor(rs, 16);
            rs += __shfl_xor(rs, 32);
            l_i += rs;
        } else {
            const float mn    = fmaxf(m_i, mx);
            const float alpha = __expf(m_i - mn);
            float rs = 0.f;
            #pragma unroll
            for (int nt = 0; nt < 4; ++nt)
                #pragma unroll
                for (int r = 0; r < 4; ++r) {
                    float p = __expf(s[nt][r] - mn);
                    s[nt][r] = p;
                    rs += p;
                }
            rs += __shfl_xor(rs, 16);
            rs += __shfl_xor(rs, 32);
            l_i = l_i * alpha + rs;
            m_i = mn;
            #pragma unroll
            for (int dt = 0; dt < 8; ++dt)
                #pragma unroll
                for (int r = 0; r < 4; ++r)
                    oacc[dt][r] *= alpha;     // per-lane alpha: no broadcast
        }

        // ---- P -> LDS, wave-private (bf16x4 vector stores; no block
        // barrier: same-wave lgkmcnt ordering covers the dependency).
        bf16_t* pw = &lds_p[wid * 16 * P_STRIDE];
        #pragma unroll
        for (int nt = 0; nt < 4; ++nt) {
            bf16x4 w;
            #pragma unroll
            for (int r = 0; r < 4; ++r) w[r] = (bf16_t)s[nt][r];
            *reinterpret_cast<bf16x4*>(&pw[l16 * P_STRIDE + nt * 16 + quad * 4]) = w;
        }

        // ---- O^T += V^T P^T
        __builtin_amdgcn_s_setprio(1);
        #pragma unroll
        for (int kc = 0; kc < 2; ++kc) {
            bf16x8 pf = *reinterpret_cast<const bf16x8*>(
                &pw[l16 * P_STRIDE + kc * 32 + quad * 8]);
            #pragma unroll
            for (int dt = 0; dt < 8; ++dt) {
                bf16x8 vf = *reinterpret_cast<const bf16x8*>(
                    &lds_v[(dt * 16 + l16) * V_STRIDE + kc * 32 + quad * 8]);
                oacc[dt] = __builtin_amdgcn_mfma_f32_16x16x32_bf16(vf, pf, oacc[dt], 0, 0, 0);
            }
        }
        __builtin_amdgcn_s_setprio(0);

        __syncthreads();                  // all waves done reading K/V LDS

        // ---- commit prefetched tile to LDS (waitcnt lands here, after
        // the load latency was hidden under the compute above)
        if (more) {
            #pragma unroll
            for (int it = 0; it < 8; ++it) {
                bf16x4 w;
                #pragma unroll
                for (int j = 0; j < 4; ++j) w[j] = (bf16_t)kbuf[it][j];
                *reinterpret_cast<bf16x4*>(&kw[it * 8 * K_STRIDE]) = w;
            }
            #pragma unroll
            for (int it = 0; it < 8; ++it)
                #pragma unroll
                for (int j = 0; j < 4; ++j)
                    vw[(it * 4 + j) * V_STRIDE] = (bf16_t)vbuf[it][j];
        }
        __syncthreads();                  // staged tile visible
    }

    // ---- epilogue: O /= l, store FP32 as f32x4 (d = dt*16 + quad*4 + r)
    const float inv = 1.0f / l_i;
    float* op = og + ((tok0 + qrow) * H_ + h) * D_;
    #pragma unroll
    for (int dt = 0; dt < 8; ++dt) {
        f32x4 o;
        #pragma unroll
        for (int r = 0; r < 4; ++r) o[r] = oacc[dt][r] * inv;
        *reinterpret_cast<f32x4*>(&op[dt * 16 + quad * 4]) = o;
    }
}

extern "C" void kernel_launch(void* const* d_in, const int* in_sizes, int n_in,
                              void* d_out, int out_size, void* d_ws, size_t ws_size,
                              hipStream_t stream) {
    const float* q = (const float*)d_in[0];   // fp32 (proven R5)
    const float* k = (const float*)d_in[1];
    const float* v = (const float*)d_in[2];
    float* out = (float*)d_out;               // fp32, per reference dtype

    const int B = in_sizes[3] - 1;
    const int T = in_sizes[0] / (H_ * D_);
    const int S = T / B;

    dim3 grid(S / BM, H_, B);
    fa_fwd<<<grid, 256, 0, stream>>>(q, k, v, out, S);
}